// Round 15
// baseline (108.162 us; speedup 1.0000x reference)
//
#include <hip/hip_runtime.h>
#include <hip/hip_bf16.h>

#define N_NODES 50000
#define N_EDGES 800000
#define D 128
#define NEG 0.2f

#define NB 200          // histogram blocks
#define EPB 4000        // edges per hist block = N_EDGES / NB
#define NPAIR 12500     // N_NODES / 4 packed u8 quads
#define NCH 8           // colscan chunks
#define ROWS_PER_CH 25  // NB / NCH

#define MFMA_BLOCKS 1563  // block-stride MFMA role: 2 tiles/block (was 768/~4;
                          // R13 PMC: 31% occupancy long-tail after fill drains)
#define NTILES 3125       // N_NODES / 16
#define COLA_BLOCKS 391   // ceil(NCH*NPAIR / 256)
#define XCONV_BLOCKS 6250 // N_NODES*D/4 float4s / 256 threads
#define FILL_SLICES 1600
#define FILL_EPS 500      // edges per fill slice

typedef __attribute__((ext_vector_type(8))) short bf16x8;
typedef __attribute__((ext_vector_type(4))) float f32x4;

__device__ __forceinline__ float bflo(unsigned int u) {
    return __uint_as_float(u << 16);
}
__device__ __forceinline__ float bfhi(unsigned int u) {
    return __uint_as_float(u & 0xffff0000u);
}

__device__ __forceinline__ ushort4 cvt4(const float4& v) {
    ushort4 o;
    __hip_bfloat16 h;
    h = __float2bfloat16(v.x); o.x = reinterpret_cast<unsigned short&>(h);
    h = __float2bfloat16(v.y); o.y = reinterpret_cast<unsigned short&>(h);
    h = __float2bfloat16(v.z); o.z = reinterpret_cast<unsigned short&>(h);
    h = __float2bfloat16(v.w); o.w = reinterpret_cast<unsigned short&>(h);
    return o;
}

// ---------------------------------------------------------------------------
// K1: blocks 0..NB-1: per-block u8-packed LDS histogram. blocks NB..NB+31:
// weights -> bf16 wb[256][128]. blocks NB+32..: x (f32) -> xb (bf16)
// streaming pass co-scheduled with the latency-bound hist blocks.
// ---------------------------------------------------------------------------
__global__ __launch_bounds__(256) void hist_convert_kernel(
    const int* __restrict__ dst_idx,
    unsigned int* __restrict__ bh,
    unsigned char* __restrict__ rank8,
    const float4* __restrict__ ws4, const float4* __restrict__ wn4,
    ushort4* __restrict__ wb4,
    const float4* __restrict__ x4, ushort4* __restrict__ xb4) {
    __shared__ unsigned int lh[NPAIR];
    const int tid = threadIdx.x, b = blockIdx.x;
    if (b < NB) {
        for (int i = tid; i < NPAIR; i += 256) lh[i] = 0u;
        __syncthreads();
        const int e0 = b * EPB;
        for (int i = tid; i < EPB; i += 256) {
            int d = dst_idx[e0 + i];
            int sh = (d & 3) * 8;
            unsigned int old = atomicAdd(&lh[d >> 2], 1u << sh);
            rank8[e0 + i] = (unsigned char)((old >> sh) & 0xffu);
        }
        __syncthreads();
        for (int i = tid; i < NPAIR; i += 256) bh[(size_t)b * NPAIR + i] = lh[i];
    } else if (b < NB + 32) {
        int i = (b - NB) * 256 + tid;
        const int NW = D * D / 4;  // 4096
        if (i < 2 * NW) {
            float4 v = (i < NW) ? ws4[i] : wn4[i - NW];
            wb4[i] = cvt4(v);
        }
    } else {
        int i = (b - NB - 32) * 256 + tid;
        if (i < N_NODES * D / 4) xb4[i] = cvt4(x4[i]);
    }
}

// ---------------------------------------------------------------------------
// K2: colscan_a, standalone (391 blocks): per-chunk column sums of bh.
// ---------------------------------------------------------------------------
__global__ __launch_bounds__(256) void colA_kernel(
    const unsigned int* __restrict__ bh, unsigned int* __restrict__ csum) {
    int gid = blockIdx.x * 256 + threadIdx.x;
    if (gid >= NCH * NPAIR) return;
    int c = gid / NPAIR;
    int i = gid - c * NPAIR;
    const unsigned int* col = bh + (size_t)(c * ROWS_PER_CH) * NPAIR + i;
    unsigned int s = 0u;
#pragma unroll
    for (int r = 0; r < ROWS_PER_CH; ++r) s += col[(size_t)r * NPAIR];
    csum[c * NPAIR + i] = s;
}

// ---------------------------------------------------------------------------
// K3 (1024 threads): blocks 0..97: in-place exclusive block-prefix within
// each column chunk. block 98: scan of per-quad totals -> offs[N+1 sentinel].
// ---------------------------------------------------------------------------
__global__ __launch_bounds__(1024) void colscanb_scan_kernel(
    unsigned int* __restrict__ bh, const unsigned int* __restrict__ csum,
    int* __restrict__ offs) {
    const int tid = threadIdx.x;
    if (blockIdx.x < 98) {
        int gid = blockIdx.x * 1024 + tid;
        if (gid >= NCH * NPAIR) return;
        int c = gid / NPAIR;
        int i = gid - c * NPAIR;
        unsigned int run = 0u;
        for (int cc = 0; cc < c; ++cc) run += csum[cc * NPAIR + i];
        unsigned int* col = bh + (size_t)(c * ROWS_PER_CH) * NPAIR + i;
#pragma unroll
        for (int r = 0; r < ROWS_PER_CH; ++r) {
            unsigned int v = col[(size_t)r * NPAIR];
            col[(size_t)r * NPAIR] = run;
            run += v;
        }
        return;
    }
    __shared__ int wsum[16];
    __shared__ int carry_s;
    const int lane = tid & 63, wv = tid >> 6;
    if (tid == 0) { carry_s = 0; offs[N_NODES] = N_EDGES; }
    __syncthreads();
    for (int base = 0; base < NPAIR; base += 4096) {
        int i0 = base + tid * 4;
        unsigned int p0 = 0, p1 = 0, p2 = 0, p3 = 0;
#pragma unroll
        for (int j = 0; j < 4; ++j) {
            int qi = i0 + j;
            if (qi < NPAIR) {
                unsigned int s = 0;
#pragma unroll
                for (int c = 0; c < NCH; ++c) s += csum[c * NPAIR + qi];
                if (j == 0) p0 = s; else if (j == 1) p1 = s;
                else if (j == 2) p2 = s; else p3 = s;
            }
        }
        int q0 = (int)((p0 & 0xffu) + ((p0 >> 8) & 0xffu) + ((p0 >> 16) & 0xffu) + (p0 >> 24));
        int q1 = (int)((p1 & 0xffu) + ((p1 >> 8) & 0xffu) + ((p1 >> 16) & 0xffu) + (p1 >> 24));
        int q2 = (int)((p2 & 0xffu) + ((p2 >> 8) & 0xffu) + ((p2 >> 16) & 0xffu) + (p2 >> 24));
        int q3 = (int)((p3 & 0xffu) + ((p3 >> 8) & 0xffu) + ((p3 >> 16) & 0xffu) + (p3 >> 24));
        int tsum = q0 + q1 + q2 + q3;
        int xs = tsum;
#pragma unroll
        for (int off = 1; off < 64; off <<= 1) {
            int y = __shfl_up(xs, off);
            if (lane >= off) xs += y;
        }
        if (lane == 63) wsum[wv] = xs;
        __syncthreads();
        if (wv == 0 && lane < 16) {
            int s = wsum[lane];
#pragma unroll
            for (int off = 1; off < 16; off <<= 1) {
                int y = __shfl_up(s, off);
                if (lane >= off) s += y;
            }
            wsum[lane] = s;
        }
        __syncthreads();
        int waveoff = (wv == 0) ? 0 : wsum[wv - 1];
        int excl = carry_s + waveoff + xs - tsum;
        unsigned int pk[4] = {p0, p1, p2, p3};
        int qs[4] = {q0, q1, q2, q3};
        int qbase = excl;
#pragma unroll
        for (int j = 0; j < 4; ++j) {
            int qi = i0 + j;
            if (qi < NPAIR) {
                unsigned int p = pk[j];
                int d0 = (int)(p & 0xffu), d1 = (int)((p >> 8) & 0xffu);
                int d2 = (int)((p >> 16) & 0xffu);
                int4 o; o.x = qbase; o.y = o.x + d0; o.z = o.y + d1; o.w = o.z + d2;
                *(int4*)(offs + 4 * qi) = o;
            }
            qbase += qs[j];
        }
        int total = wsum[15];
        __syncthreads();
        if (tid == 0) carry_s += total;
        __syncthreads();
    }
}

// ---------------------------------------------------------------------------
// K4: fused MFMA + fill. blocks 0..MFMA_BLOCKS-1: MFMA dual transform
// (round-12 verified body; now 2 tiles/block for 2x tail parallelism);
// blocks MFMA_BLOCKS..+1599: lean fill (verbatim).
// ---------------------------------------------------------------------------
__global__ __launch_bounds__(256) void mfma_fill_kernel(
    const ushort* __restrict__ xb, const ushort* __restrict__ wb,
    unsigned int* __restrict__ sb32, unsigned int* __restrict__ zb32,
    const int* __restrict__ dst_idx, const int* __restrict__ src_idx,
    const unsigned char* __restrict__ rank8,
    const unsigned char* __restrict__ bprefix,
    const int* __restrict__ offs, unsigned short* __restrict__ adj) {
    __shared__ ushort tile[2][16][132];  // [s|z][row][col padded]
    if (blockIdx.x < MFMA_BLOCKS) {
        const int lane = threadIdx.x & 63;
        const int wv = threadIdx.x >> 6;
        const int lm = lane & 15;
        const int lk = (lane >> 4) * 8;
        const int dr = (lane >> 4) * 4;

        // hoisted B fragments: wave wv owns col-tiles nt = 4wv..4wv+3
        bf16x8 b[4][4];
#pragma unroll
        for (int t4 = 0; t4 < 4; ++t4) {
            const int nt = wv * 4 + t4;
#pragma unroll
            for (int kc = 0; kc < 4; ++kc)
                b[t4][kc] = *(const bf16x8*)(wb + (nt * 16 + lm) * D + kc * 32 + lk);
        }

        for (int t = blockIdx.x; t < NTILES; t += MFMA_BLOCKS) {
            const int m0 = t * 16;

            // A fragments: direct bf16 loads (16B per k-chunk)
            bf16x8 a[4];
#pragma unroll
            for (int kc = 0; kc < 4; ++kc)
                a[kc] = *(const bf16x8*)(xb + (size_t)(m0 + lm) * D + kc * 32 + lk);

#pragma unroll
            for (int t4 = 0; t4 < 4; ++t4) {
                const int nt = wv * 4 + t4;
                f32x4 acc = {0.f, 0.f, 0.f, 0.f};
#pragma unroll
                for (int kc = 0; kc < 4; ++kc)
                    acc = __builtin_amdgcn_mfma_f32_16x16x32_bf16(a[kc], b[t4][kc], acc, 0, 0, 0);
                ushort (*tptr)[132] = (nt < 8) ? tile[0] : tile[1];
                const int col = (nt & 7) * 16 + lm;
#pragma unroll
                for (int r = 0; r < 4; ++r) {
                    __hip_bfloat16 h = __float2bfloat16(acc[r]);
                    tptr[dr + r][col] = reinterpret_cast<unsigned short&>(h);
                }
            }
            __syncthreads();
            const unsigned int* ts32 = (const unsigned int*)tile[0];
            const unsigned int* tz32 = (const unsigned int*)tile[1];
#pragma unroll
            for (int q = 0; q < 4; ++q) {
                const int r16 = wv * 4 + q;
                sb32[(m0 + r16) * 64 + lane] = ts32[r16 * 66 + lane];
                zb32[(m0 + r16) * 64 + lane] = tz32[r16 * 66 + lane];
            }
            __syncthreads();  // tile reused next iteration
        }
    } else {
        const int e0 = (blockIdx.x - MFMA_BLOCKS) * FILL_EPS;
        const int b = e0 / EPB;
        const unsigned char* bp = bprefix + (size_t)b * N_NODES;
        for (int i = threadIdx.x; i < FILL_EPS; i += 256) {
            int e = e0 + i;
            int d = dst_idx[e];
            int pos = offs[d] + (int)bp[d] + (int)rank8[e];
            adj[pos] = (unsigned short)src_idx[e];
        }
    }
}

// ---------------------------------------------------------------------------
// K5: gather-finalize, 16-deep main loop (round-14 verified, ~33us;
// fabric-bound on random 256B rows).
// ---------------------------------------------------------------------------
__global__ __launch_bounds__(256) void gather_final_kernel(
    const uint4* __restrict__ zb4, const uint4* __restrict__ sb4,
    const int* __restrict__ offs,
    const unsigned short* __restrict__ adj, float4* __restrict__ out4) {
    int wid = (int)((blockIdx.x * (long)blockDim.x + threadIdx.x) >> 6);
    int lane = threadIdx.x & 63;
    if (wid >= N_NODES) return;
    const int c = lane & 15, g = lane >> 4;
    int base = offs[wid];
    int len = offs[wid + 1] - base;

    float a0 = 0.f, a1 = 0.f, a2 = 0.f, a3 = 0.f;
    float a4 = 0.f, a5 = 0.f, a6 = 0.f, a7 = 0.f;

    int k = 0;
    for (; k + 16 <= len; k += 16) {
        unsigned int s0 = adj[base + k + g];
        unsigned int s1 = adj[base + k + 4 + g];
        unsigned int s2 = adj[base + k + 8 + g];
        unsigned int s3 = adj[base + k + 12 + g];
        uint4 v0 = zb4[s0 * 16u + c];
        uint4 v1 = zb4[s1 * 16u + c];
        uint4 v2 = zb4[s2 * 16u + c];
        uint4 v3 = zb4[s3 * 16u + c];
        a0 += bflo(v0.x); a1 += bfhi(v0.x);
        a2 += bflo(v0.y); a3 += bfhi(v0.y);
        a4 += bflo(v0.z); a5 += bfhi(v0.z);
        a6 += bflo(v0.w); a7 += bfhi(v0.w);
        a0 += bflo(v1.x); a1 += bfhi(v1.x);
        a2 += bflo(v1.y); a3 += bfhi(v1.y);
        a4 += bflo(v1.z); a5 += bfhi(v1.z);
        a6 += bflo(v1.w); a7 += bfhi(v1.w);
        a0 += bflo(v2.x); a1 += bfhi(v2.x);
        a2 += bflo(v2.y); a3 += bfhi(v2.y);
        a4 += bflo(v2.z); a5 += bfhi(v2.z);
        a6 += bflo(v2.w); a7 += bfhi(v2.w);
        a0 += bflo(v3.x); a1 += bfhi(v3.x);
        a2 += bflo(v3.y); a3 += bfhi(v3.y);
        a4 += bflo(v3.z); a5 += bfhi(v3.z);
        a6 += bflo(v3.w); a7 += bfhi(v3.w);
    }
    if (k + 8 <= len) {
        unsigned int sA = adj[base + k + g];
        unsigned int sB = adj[base + k + 4 + g];
        uint4 vA = zb4[sA * 16u + c];
        uint4 vB = zb4[sB * 16u + c];
        a0 += bflo(vA.x); a1 += bfhi(vA.x);
        a2 += bflo(vA.y); a3 += bfhi(vA.y);
        a4 += bflo(vA.z); a5 += bfhi(vA.z);
        a6 += bflo(vA.w); a7 += bfhi(vA.w);
        a0 += bflo(vB.x); a1 += bfhi(vB.x);
        a2 += bflo(vB.y); a3 += bfhi(vB.y);
        a4 += bflo(vB.z); a5 += bfhi(vB.z);
        a6 += bflo(vB.w); a7 += bfhi(vB.w);
        k += 8;
    }
    if (k + 4 <= len) {
        unsigned int sA = adj[base + k + g];
        uint4 vA = zb4[sA * 16u + c];
        a0 += bflo(vA.x); a1 += bfhi(vA.x);
        a2 += bflo(vA.y); a3 += bfhi(vA.y);
        a4 += bflo(vA.z); a5 += bfhi(vA.z);
        a6 += bflo(vA.w); a7 += bfhi(vA.w);
        k += 4;
    }
    int rem = len - k;
    if (g < rem) {
        unsigned int sA = adj[base + k + g];
        uint4 vA = zb4[sA * 16u + c];
        a0 += bflo(vA.x); a1 += bfhi(vA.x);
        a2 += bflo(vA.y); a3 += bfhi(vA.y);
        a4 += bflo(vA.z); a5 += bfhi(vA.z);
        a6 += bflo(vA.w); a7 += bfhi(vA.w);
    }

    // fold the 4 neighbor groups
    a0 += __shfl_xor(a0, 16); a1 += __shfl_xor(a1, 16);
    a2 += __shfl_xor(a2, 16); a3 += __shfl_xor(a3, 16);
    a4 += __shfl_xor(a4, 16); a5 += __shfl_xor(a5, 16);
    a6 += __shfl_xor(a6, 16); a7 += __shfl_xor(a7, 16);
    a0 += __shfl_xor(a0, 32); a1 += __shfl_xor(a1, 32);
    a2 += __shfl_xor(a2, 32); a3 += __shfl_xor(a3, 32);
    a4 += __shfl_xor(a4, 32); a5 += __shfl_xor(a5, 32);
    a6 += __shfl_xor(a6, 32); a7 += __shfl_xor(a7, 32);

    float inv = 1.0f / fmaxf((float)len, 1.0f);
    float m0 = a0 * inv, m1 = a1 * inv, m2 = a2 * inv, m3 = a3 * inv;
    float m4 = a4 * inv, m5 = a5 * inv, m6 = a6 * inv, m7 = a7 * inv;
    m0 = m0 > 0.f ? m0 : NEG * m0; m1 = m1 > 0.f ? m1 : NEG * m1;
    m2 = m2 > 0.f ? m2 : NEG * m2; m3 = m3 > 0.f ? m3 : NEG * m3;
    m4 = m4 > 0.f ? m4 : NEG * m4; m5 = m5 > 0.f ? m5 : NEG * m5;
    m6 = m6 > 0.f ? m6 : NEG * m6; m7 = m7 > 0.f ? m7 : NEG * m7;

    uint4 sv = sb4[(unsigned int)wid * 16u + c];
    float u0 = bflo(sv.x) + m0, u1 = bfhi(sv.x) + m1;
    float u2 = bflo(sv.y) + m2, u3 = bfhi(sv.y) + m3;
    float u4 = bflo(sv.z) + m4, u5 = bfhi(sv.z) + m5;
    float u6 = bflo(sv.w) + m6, u7 = bfhi(sv.w) + m7;
    u0 = u0 > 0.f ? u0 : NEG * u0; u1 = u1 > 0.f ? u1 : NEG * u1;
    u2 = u2 > 0.f ? u2 : NEG * u2; u3 = u3 > 0.f ? u3 : NEG * u3;
    u4 = u4 > 0.f ? u4 : NEG * u4; u5 = u5 > 0.f ? u5 : NEG * u5;
    u6 = u6 > 0.f ? u6 : NEG * u6; u7 = u7 > 0.f ? u7 : NEG * u7;

    float ss = u0 * u0 + u1 * u1 + u2 * u2 + u3 * u3 +
               u4 * u4 + u5 * u5 + u6 * u6 + u7 * u7;
    ss += __shfl_xor(ss, 1);
    ss += __shfl_xor(ss, 2);
    ss += __shfl_xor(ss, 4);
    ss += __shfl_xor(ss, 8);
    float r = 1.0f / fmaxf(sqrtf(ss), 1e-12f);

    if (lane < 16) {
        float4 o0; o0.x = u0 * r; o0.y = u1 * r; o0.z = u2 * r; o0.w = u3 * r;
        float4 o1; o1.x = u4 * r; o1.y = u5 * r; o1.z = u6 * r; o1.w = u7 * r;
        out4[(unsigned int)wid * 32u + c * 2u] = o0;
        out4[(unsigned int)wid * 32u + c * 2u + 1u] = o1;
    }
}

extern "C" void kernel_launch(void* const* d_in, const int* in_sizes, int n_in,
                              void* d_out, int out_size, void* d_ws, size_t ws_size,
                              hipStream_t stream) {
    const float* node_fts = (const float*)d_in[0];
    const int* edges = (const int*)d_in[1];
    const float* W_self = (const float*)d_in[3];
    const float* W_neigh = (const float*)d_in[4];

    const int* dst_idx = edges;            // edges[0,:]
    const int* src_idx = edges + N_EDGES;  // edges[1,:]

    // ws layout:
    // zb[N*D u16] | sb[N*D u16] | wb[256*128 u16] | xb[N*D u16] |
    // offs[N+1] | adj[E u16] | bh[NB*NPAIR u32] | rank8[E] | csum[8*NPAIR u32]
    unsigned short* zb = (unsigned short*)d_ws;
    unsigned short* sb = zb + (size_t)N_NODES * D;
    unsigned short* wb = sb + (size_t)N_NODES * D;
    unsigned short* xb = wb + 256 * 128;
    int* offs = (int*)(xb + (size_t)N_NODES * D);
    unsigned short* adj = (unsigned short*)(offs + N_NODES + 1);
    unsigned int* bh = (unsigned int*)(adj + N_EDGES);
    unsigned char* rank8 = (unsigned char*)(bh + (size_t)NB * NPAIR);
    unsigned int* csum = (unsigned int*)(rank8 + N_EDGES);

    // K1: hist (200) + weight convert (32) + x convert (6250)
    hist_convert_kernel<<<NB + 32 + XCONV_BLOCKS, 256, 0, stream>>>(
        dst_idx, bh, rank8,
        (const float4*)W_self, (const float4*)W_neigh, (ushort4*)wb,
        (const float4*)node_fts, (ushort4*)xb);

    // K2: colscan_a (391 blocks; needs completed bh)
    colA_kernel<<<COLA_BLOCKS, 256, 0, stream>>>(bh, csum);

    // K3: column block-prefix (98 blocks) + quad scan -> offs (1 block)
    colscanb_scan_kernel<<<99, 1024, 0, stream>>>(bh, csum, offs);

    // K4: MFMA (1563 blocks, 2 tiles each) + fill (1600 blocks) — overlapped.
    mfma_fill_kernel<<<MFMA_BLOCKS + FILL_SLICES, 256, 0, stream>>>(
        xb, wb, (unsigned int*)sb, (unsigned int*)zb,
        dst_idx, src_idx, rank8, (const unsigned char*)bh, offs, adj);

    // K5: wide gather (16-deep) + mean + leaky + combine + leaky + L2 norm
    int gb = (N_NODES * 64 + 255) / 256;
    gather_final_kernel<<<gb, 256, 0, stream>>>(
        (const uint4*)zb, (const uint4*)sb, offs, adj, (float4*)d_out);
}

// Round 16
// 99.895 us; speedup vs baseline: 1.0827x; 1.0827x over previous
//
#include <hip/hip_runtime.h>
#include <hip/hip_bf16.h>

#define N_NODES 50000
#define N_EDGES 800000
#define D 128
#define NEG 0.2f

#define NB 200          // histogram blocks
#define EPB 4000        // edges per hist block = N_EDGES / NB
#define NPAIR 12500     // N_NODES / 4 packed u8 quads
#define NCH 8           // colscan chunks
#define ROWS_PER_CH 25  // NB / NCH

#define MFMA_BLOCKS 768   // REVERTED to R14 (R15: 1563 blocks = +4.3us, fixed
                          // per-block wb-hoist cost dominates; contention-bound)
#define NTILES 3125       // N_NODES / 16
#define COLA_BLOCKS 391   // ceil(NCH*NPAIR / 256)
#define WCONV_BLOCKS 16   // 8192 float4s / 512 threads
#define XCONV_BLOCKS 3125 // N_NODES*D/4 float4s / 512 threads
#define FILL_SLICES 1600
#define FILL_EPS 500      // edges per fill slice

typedef __attribute__((ext_vector_type(8))) short bf16x8;
typedef __attribute__((ext_vector_type(4))) float f32x4;

__device__ __forceinline__ float bflo(unsigned int u) {
    return __uint_as_float(u << 16);
}
__device__ __forceinline__ float bfhi(unsigned int u) {
    return __uint_as_float(u & 0xffff0000u);
}

__device__ __forceinline__ ushort4 cvt4(const float4& v) {
    ushort4 o;
    __hip_bfloat16 h;
    h = __float2bfloat16(v.x); o.x = reinterpret_cast<unsigned short&>(h);
    h = __float2bfloat16(v.y); o.y = reinterpret_cast<unsigned short&>(h);
    h = __float2bfloat16(v.z); o.z = reinterpret_cast<unsigned short&>(h);
    h = __float2bfloat16(v.w); o.w = reinterpret_cast<unsigned short&>(h);
    return o;
}

// ---------------------------------------------------------------------------
// K1 (512 threads — NEW): the 200 hist blocks are <1/CU, so their duration
// is the per-block SERIAL iteration count (zero 12500 LDS words + atomic
// pass + write-out). 512 threads halves each serial chain. wconv/xconv
// roles are streams, unaffected. (Rank order within a (block,node) group
// changes -> adj permutes within a dst segment; fp32 gather-sum ~1e-7.)
// blocks 0..199: u8-packed LDS histogram. blocks 200..215: weights -> wb.
// blocks 216..3340: x (f32) -> xb (bf16) stream.
// ---------------------------------------------------------------------------
__global__ __launch_bounds__(512) void hist_convert_kernel(
    const int* __restrict__ dst_idx,
    unsigned int* __restrict__ bh,
    unsigned char* __restrict__ rank8,
    const float4* __restrict__ ws4, const float4* __restrict__ wn4,
    ushort4* __restrict__ wb4,
    const float4* __restrict__ x4, ushort4* __restrict__ xb4) {
    __shared__ unsigned int lh[NPAIR];
    const int tid = threadIdx.x, b = blockIdx.x;
    if (b < NB) {
        for (int i = tid; i < NPAIR; i += 512) lh[i] = 0u;
        __syncthreads();
        const int e0 = b * EPB;
        for (int i = tid; i < EPB; i += 512) {
            int d = dst_idx[e0 + i];
            int sh = (d & 3) * 8;
            unsigned int old = atomicAdd(&lh[d >> 2], 1u << sh);
            rank8[e0 + i] = (unsigned char)((old >> sh) & 0xffu);
        }
        __syncthreads();
        for (int i = tid; i < NPAIR; i += 512) bh[(size_t)b * NPAIR + i] = lh[i];
    } else if (b < NB + WCONV_BLOCKS) {
        int i = (b - NB) * 512 + tid;
        const int NW = D * D / 4;  // 4096
        if (i < 2 * NW) {
            float4 v = (i < NW) ? ws4[i] : wn4[i - NW];
            wb4[i] = cvt4(v);
        }
    } else {
        int i = (b - NB - WCONV_BLOCKS) * 512 + tid;
        if (i < N_NODES * D / 4) xb4[i] = cvt4(x4[i]);
    }
}

// ---------------------------------------------------------------------------
// K2: colscan_a, standalone (391 blocks): per-chunk column sums of bh.
// ---------------------------------------------------------------------------
__global__ __launch_bounds__(256) void colA_kernel(
    const unsigned int* __restrict__ bh, unsigned int* __restrict__ csum) {
    int gid = blockIdx.x * 256 + threadIdx.x;
    if (gid >= NCH * NPAIR) return;
    int c = gid / NPAIR;
    int i = gid - c * NPAIR;
    const unsigned int* col = bh + (size_t)(c * ROWS_PER_CH) * NPAIR + i;
    unsigned int s = 0u;
#pragma unroll
    for (int r = 0; r < ROWS_PER_CH; ++r) s += col[(size_t)r * NPAIR];
    csum[c * NPAIR + i] = s;
}

// ---------------------------------------------------------------------------
// K3 (1024 threads): blocks 0..97: in-place exclusive block-prefix within
// each column chunk. block 98: scan of per-quad totals -> offs[N+1 sentinel].
// ---------------------------------------------------------------------------
__global__ __launch_bounds__(1024) void colscanb_scan_kernel(
    unsigned int* __restrict__ bh, const unsigned int* __restrict__ csum,
    int* __restrict__ offs) {
    const int tid = threadIdx.x;
    if (blockIdx.x < 98) {
        int gid = blockIdx.x * 1024 + tid;
        if (gid >= NCH * NPAIR) return;
        int c = gid / NPAIR;
        int i = gid - c * NPAIR;
        unsigned int run = 0u;
        for (int cc = 0; cc < c; ++cc) run += csum[cc * NPAIR + i];
        unsigned int* col = bh + (size_t)(c * ROWS_PER_CH) * NPAIR + i;
#pragma unroll
        for (int r = 0; r < ROWS_PER_CH; ++r) {
            unsigned int v = col[(size_t)r * NPAIR];
            col[(size_t)r * NPAIR] = run;
            run += v;
        }
        return;
    }
    __shared__ int wsum[16];
    __shared__ int carry_s;
    const int lane = tid & 63, wv = tid >> 6;
    if (tid == 0) { carry_s = 0; offs[N_NODES] = N_EDGES; }
    __syncthreads();
    for (int base = 0; base < NPAIR; base += 4096) {
        int i0 = base + tid * 4;
        unsigned int p0 = 0, p1 = 0, p2 = 0, p3 = 0;
#pragma unroll
        for (int j = 0; j < 4; ++j) {
            int qi = i0 + j;
            if (qi < NPAIR) {
                unsigned int s = 0;
#pragma unroll
                for (int c = 0; c < NCH; ++c) s += csum[c * NPAIR + qi];
                if (j == 0) p0 = s; else if (j == 1) p1 = s;
                else if (j == 2) p2 = s; else p3 = s;
            }
        }
        int q0 = (int)((p0 & 0xffu) + ((p0 >> 8) & 0xffu) + ((p0 >> 16) & 0xffu) + (p0 >> 24));
        int q1 = (int)((p1 & 0xffu) + ((p1 >> 8) & 0xffu) + ((p1 >> 16) & 0xffu) + (p1 >> 24));
        int q2 = (int)((p2 & 0xffu) + ((p2 >> 8) & 0xffu) + ((p2 >> 16) & 0xffu) + (p2 >> 24));
        int q3 = (int)((p3 & 0xffu) + ((p3 >> 8) & 0xffu) + ((p3 >> 16) & 0xffu) + (p3 >> 24));
        int tsum = q0 + q1 + q2 + q3;
        int xs = tsum;
#pragma unroll
        for (int off = 1; off < 64; off <<= 1) {
            int y = __shfl_up(xs, off);
            if (lane >= off) xs += y;
        }
        if (lane == 63) wsum[wv] = xs;
        __syncthreads();
        if (wv == 0 && lane < 16) {
            int s = wsum[lane];
#pragma unroll
            for (int off = 1; off < 16; off <<= 1) {
                int y = __shfl_up(s, off);
                if (lane >= off) s += y;
            }
            wsum[lane] = s;
        }
        __syncthreads();
        int waveoff = (wv == 0) ? 0 : wsum[wv - 1];
        int excl = carry_s + waveoff + xs - tsum;
        unsigned int pk[4] = {p0, p1, p2, p3};
        int qs[4] = {q0, q1, q2, q3};
        int qbase = excl;
#pragma unroll
        for (int j = 0; j < 4; ++j) {
            int qi = i0 + j;
            if (qi < NPAIR) {
                unsigned int p = pk[j];
                int d0 = (int)(p & 0xffu), d1 = (int)((p >> 8) & 0xffu);
                int d2 = (int)((p >> 16) & 0xffu);
                int4 o; o.x = qbase; o.y = o.x + d0; o.z = o.y + d1; o.w = o.z + d2;
                *(int4*)(offs + 4 * qi) = o;
            }
            qbase += qs[j];
        }
        int total = wsum[15];
        __syncthreads();
        if (tid == 0) carry_s += total;
        __syncthreads();
    }
}

// ---------------------------------------------------------------------------
// K4: fused MFMA + fill (R14 verified config: 768 MFMA blocks, ~4 tiles
// each; 1600 fill blocks). Measured ~40us, contention-bound (R15).
// ---------------------------------------------------------------------------
__global__ __launch_bounds__(256) void mfma_fill_kernel(
    const ushort* __restrict__ xb, const ushort* __restrict__ wb,
    unsigned int* __restrict__ sb32, unsigned int* __restrict__ zb32,
    const int* __restrict__ dst_idx, const int* __restrict__ src_idx,
    const unsigned char* __restrict__ rank8,
    const unsigned char* __restrict__ bprefix,
    const int* __restrict__ offs, unsigned short* __restrict__ adj) {
    __shared__ ushort tile[2][16][132];  // [s|z][row][col padded]
    if (blockIdx.x < MFMA_BLOCKS) {
        const int lane = threadIdx.x & 63;
        const int wv = threadIdx.x >> 6;
        const int lm = lane & 15;
        const int lk = (lane >> 4) * 8;
        const int dr = (lane >> 4) * 4;

        // hoisted B fragments: wave wv owns col-tiles nt = 4wv..4wv+3
        bf16x8 b[4][4];
#pragma unroll
        for (int t4 = 0; t4 < 4; ++t4) {
            const int nt = wv * 4 + t4;
#pragma unroll
            for (int kc = 0; kc < 4; ++kc)
                b[t4][kc] = *(const bf16x8*)(wb + (nt * 16 + lm) * D + kc * 32 + lk);
        }

        for (int t = blockIdx.x; t < NTILES; t += MFMA_BLOCKS) {
            const int m0 = t * 16;

            // A fragments: direct bf16 loads (16B per k-chunk)
            bf16x8 a[4];
#pragma unroll
            for (int kc = 0; kc < 4; ++kc)
                a[kc] = *(const bf16x8*)(xb + (size_t)(m0 + lm) * D + kc * 32 + lk);

#pragma unroll
            for (int t4 = 0; t4 < 4; ++t4) {
                const int nt = wv * 4 + t4;
                f32x4 acc = {0.f, 0.f, 0.f, 0.f};
#pragma unroll
                for (int kc = 0; kc < 4; ++kc)
                    acc = __builtin_amdgcn_mfma_f32_16x16x32_bf16(a[kc], b[t4][kc], acc, 0, 0, 0);
                ushort (*tptr)[132] = (nt < 8) ? tile[0] : tile[1];
                const int col = (nt & 7) * 16 + lm;
#pragma unroll
                for (int r = 0; r < 4; ++r) {
                    __hip_bfloat16 h = __float2bfloat16(acc[r]);
                    tptr[dr + r][col] = reinterpret_cast<unsigned short&>(h);
                }
            }
            __syncthreads();
            const unsigned int* ts32 = (const unsigned int*)tile[0];
            const unsigned int* tz32 = (const unsigned int*)tile[1];
#pragma unroll
            for (int q = 0; q < 4; ++q) {
                const int r16 = wv * 4 + q;
                sb32[(m0 + r16) * 64 + lane] = ts32[r16 * 66 + lane];
                zb32[(m0 + r16) * 64 + lane] = tz32[r16 * 66 + lane];
            }
            __syncthreads();  // tile reused next iteration
        }
    } else {
        const int e0 = (blockIdx.x - MFMA_BLOCKS) * FILL_EPS;
        const int b = e0 / EPB;
        const unsigned char* bp = bprefix + (size_t)b * N_NODES;
        for (int i = threadIdx.x; i < FILL_EPS; i += 256) {
            int e = e0 + i;
            int d = dst_idx[e];
            int pos = offs[d] + (int)bp[d] + (int)rank8[e];
            adj[pos] = (unsigned short)src_idx[e];
        }
    }
}

// ---------------------------------------------------------------------------
// K5: gather-finalize, 16-deep main loop (round-14 verified, ~33us;
// fabric-bound on random 256B rows).
// ---------------------------------------------------------------------------
__global__ __launch_bounds__(256) void gather_final_kernel(
    const uint4* __restrict__ zb4, const uint4* __restrict__ sb4,
    const int* __restrict__ offs,
    const unsigned short* __restrict__ adj, float4* __restrict__ out4) {
    int wid = (int)((blockIdx.x * (long)blockDim.x + threadIdx.x) >> 6);
    int lane = threadIdx.x & 63;
    if (wid >= N_NODES) return;
    const int c = lane & 15, g = lane >> 4;
    int base = offs[wid];
    int len = offs[wid + 1] - base;

    float a0 = 0.f, a1 = 0.f, a2 = 0.f, a3 = 0.f;
    float a4 = 0.f, a5 = 0.f, a6 = 0.f, a7 = 0.f;

    int k = 0;
    for (; k + 16 <= len; k += 16) {
        unsigned int s0 = adj[base + k + g];
        unsigned int s1 = adj[base + k + 4 + g];
        unsigned int s2 = adj[base + k + 8 + g];
        unsigned int s3 = adj[base + k + 12 + g];
        uint4 v0 = zb4[s0 * 16u + c];
        uint4 v1 = zb4[s1 * 16u + c];
        uint4 v2 = zb4[s2 * 16u + c];
        uint4 v3 = zb4[s3 * 16u + c];
        a0 += bflo(v0.x); a1 += bfhi(v0.x);
        a2 += bflo(v0.y); a3 += bfhi(v0.y);
        a4 += bflo(v0.z); a5 += bfhi(v0.z);
        a6 += bflo(v0.w); a7 += bfhi(v0.w);
        a0 += bflo(v1.x); a1 += bfhi(v1.x);
        a2 += bflo(v1.y); a3 += bfhi(v1.y);
        a4 += bflo(v1.z); a5 += bfhi(v1.z);
        a6 += bflo(v1.w); a7 += bfhi(v1.w);
        a0 += bflo(v2.x); a1 += bfhi(v2.x);
        a2 += bflo(v2.y); a3 += bfhi(v2.y);
        a4 += bflo(v2.z); a5 += bfhi(v2.z);
        a6 += bflo(v2.w); a7 += bfhi(v2.w);
        a0 += bflo(v3.x); a1 += bfhi(v3.x);
        a2 += bflo(v3.y); a3 += bfhi(v3.y);
        a4 += bflo(v3.z); a5 += bfhi(v3.z);
        a6 += bflo(v3.w); a7 += bfhi(v3.w);
    }
    if (k + 8 <= len) {
        unsigned int sA = adj[base + k + g];
        unsigned int sB = adj[base + k + 4 + g];
        uint4 vA = zb4[sA * 16u + c];
        uint4 vB = zb4[sB * 16u + c];
        a0 += bflo(vA.x); a1 += bfhi(vA.x);
        a2 += bflo(vA.y); a3 += bfhi(vA.y);
        a4 += bflo(vA.z); a5 += bfhi(vA.z);
        a6 += bflo(vA.w); a7 += bfhi(vA.w);
        a0 += bflo(vB.x); a1 += bfhi(vB.x);
        a2 += bflo(vB.y); a3 += bfhi(vB.y);
        a4 += bflo(vB.z); a5 += bfhi(vB.z);
        a6 += bflo(vB.w); a7 += bfhi(vB.w);
        k += 8;
    }
    if (k + 4 <= len) {
        unsigned int sA = adj[base + k + g];
        uint4 vA = zb4[sA * 16u + c];
        a0 += bflo(vA.x); a1 += bfhi(vA.x);
        a2 += bflo(vA.y); a3 += bfhi(vA.y);
        a4 += bflo(vA.z); a5 += bfhi(vA.z);
        a6 += bflo(vA.w); a7 += bfhi(vA.w);
        k += 4;
    }
    int rem = len - k;
    if (g < rem) {
        unsigned int sA = adj[base + k + g];
        uint4 vA = zb4[sA * 16u + c];
        a0 += bflo(vA.x); a1 += bfhi(vA.x);
        a2 += bflo(vA.y); a3 += bfhi(vA.y);
        a4 += bflo(vA.z); a5 += bfhi(vA.z);
        a6 += bflo(vA.w); a7 += bfhi(vA.w);
    }

    // fold the 4 neighbor groups
    a0 += __shfl_xor(a0, 16); a1 += __shfl_xor(a1, 16);
    a2 += __shfl_xor(a2, 16); a3 += __shfl_xor(a3, 16);
    a4 += __shfl_xor(a4, 16); a5 += __shfl_xor(a5, 16);
    a6 += __shfl_xor(a6, 16); a7 += __shfl_xor(a7, 16);
    a0 += __shfl_xor(a0, 32); a1 += __shfl_xor(a1, 32);
    a2 += __shfl_xor(a2, 32); a3 += __shfl_xor(a3, 32);
    a4 += __shfl_xor(a4, 32); a5 += __shfl_xor(a5, 32);
    a6 += __shfl_xor(a6, 32); a7 += __shfl_xor(a7, 32);

    float inv = 1.0f / fmaxf((float)len, 1.0f);
    float m0 = a0 * inv, m1 = a1 * inv, m2 = a2 * inv, m3 = a3 * inv;
    float m4 = a4 * inv, m5 = a5 * inv, m6 = a6 * inv, m7 = a7 * inv;
    m0 = m0 > 0.f ? m0 : NEG * m0; m1 = m1 > 0.f ? m1 : NEG * m1;
    m2 = m2 > 0.f ? m2 : NEG * m2; m3 = m3 > 0.f ? m3 : NEG * m3;
    m4 = m4 > 0.f ? m4 : NEG * m4; m5 = m5 > 0.f ? m5 : NEG * m5;
    m6 = m6 > 0.f ? m6 : NEG * m6; m7 = m7 > 0.f ? m7 : NEG * m7;

    uint4 sv = sb4[(unsigned int)wid * 16u + c];
    float u0 = bflo(sv.x) + m0, u1 = bfhi(sv.x) + m1;
    float u2 = bflo(sv.y) + m2, u3 = bfhi(sv.y) + m3;
    float u4 = bflo(sv.z) + m4, u5 = bfhi(sv.z) + m5;
    float u6 = bflo(sv.w) + m6, u7 = bfhi(sv.w) + m7;
    u0 = u0 > 0.f ? u0 : NEG * u0; u1 = u1 > 0.f ? u1 : NEG * u1;
    u2 = u2 > 0.f ? u2 : NEG * u2; u3 = u3 > 0.f ? u3 : NEG * u3;
    u4 = u4 > 0.f ? u4 : NEG * u4; u5 = u5 > 0.f ? u5 : NEG * u5;
    u6 = u6 > 0.f ? u6 : NEG * u6; u7 = u7 > 0.f ? u7 : NEG * u7;

    float ss = u0 * u0 + u1 * u1 + u2 * u2 + u3 * u3 +
               u4 * u4 + u5 * u5 + u6 * u6 + u7 * u7;
    ss += __shfl_xor(ss, 1);
    ss += __shfl_xor(ss, 2);
    ss += __shfl_xor(ss, 4);
    ss += __shfl_xor(ss, 8);
    float r = 1.0f / fmaxf(sqrtf(ss), 1e-12f);

    if (lane < 16) {
        float4 o0; o0.x = u0 * r; o0.y = u1 * r; o0.z = u2 * r; o0.w = u3 * r;
        float4 o1; o1.x = u4 * r; o1.y = u5 * r; o1.z = u6 * r; o1.w = u7 * r;
        out4[(unsigned int)wid * 32u + c * 2u] = o0;
        out4[(unsigned int)wid * 32u + c * 2u + 1u] = o1;
    }
}

extern "C" void kernel_launch(void* const* d_in, const int* in_sizes, int n_in,
                              void* d_out, int out_size, void* d_ws, size_t ws_size,
                              hipStream_t stream) {
    const float* node_fts = (const float*)d_in[0];
    const int* edges = (const int*)d_in[1];
    const float* W_self = (const float*)d_in[3];
    const float* W_neigh = (const float*)d_in[4];

    const int* dst_idx = edges;            // edges[0,:]
    const int* src_idx = edges + N_EDGES;  // edges[1,:]

    // ws layout:
    // zb[N*D u16] | sb[N*D u16] | wb[256*128 u16] | xb[N*D u16] |
    // offs[N+1] | adj[E u16] | bh[NB*NPAIR u32] | rank8[E] | csum[8*NPAIR u32]
    unsigned short* zb = (unsigned short*)d_ws;
    unsigned short* sb = zb + (size_t)N_NODES * D;
    unsigned short* wb = sb + (size_t)N_NODES * D;
    unsigned short* xb = wb + 256 * 128;
    int* offs = (int*)(xb + (size_t)N_NODES * D);
    unsigned short* adj = (unsigned short*)(offs + N_NODES + 1);
    unsigned int* bh = (unsigned int*)(adj + N_EDGES);
    unsigned char* rank8 = (unsigned char*)(bh + (size_t)NB * NPAIR);
    unsigned int* csum = (unsigned int*)(rank8 + N_EDGES);

    // K1 (512 threads): hist (200) + weight convert (16) + x convert (3125)
    hist_convert_kernel<<<NB + WCONV_BLOCKS + XCONV_BLOCKS, 512, 0, stream>>>(
        dst_idx, bh, rank8,
        (const float4*)W_self, (const float4*)W_neigh, (ushort4*)wb,
        (const float4*)node_fts, (ushort4*)xb);

    // K2: colscan_a (391 blocks; needs completed bh)
    colA_kernel<<<COLA_BLOCKS, 256, 0, stream>>>(bh, csum);

    // K3: column block-prefix (98 blocks) + quad scan -> offs (1 block)
    colscanb_scan_kernel<<<99, 1024, 0, stream>>>(bh, csum, offs);

    // K4: MFMA (768 blocks) + fill (1600 blocks) — overlapped chains.
    mfma_fill_kernel<<<MFMA_BLOCKS + FILL_SLICES, 256, 0, stream>>>(
        xb, wb, (unsigned int*)sb, (unsigned int*)zb,
        dst_idx, src_idx, rank8, (const unsigned char*)bh, offs, adj);

    // K5: wide gather (16-deep) + mean + leaky + combine + leaky + L2 norm
    int gb = (N_NODES * 64 + 255) / 256;
    gather_final_kernel<<<gb, 256, 0, stream>>>(
        (const uint4*)zb, (const uint4*)sb, offs, adj, (float4*)d_out);
}